// Round 12
// baseline (155.892 us; speedup 1.0000x reference)
//
#include <hip/hip_runtime.h>
#include <hip/hip_bf16.h>
#include <stdint.h>

// Recommender: B=4096 users, L=200 history, D=64 emb, F=100000 films.
// Kernel A (stats): ONE USER PER WAVE, lane = dim; 4 independent waves per
//   256-thread block, ZERO LDS, zero barriers. hist/rat are read at
//   wave-uniform indices from const __restrict__ memory -> compiler
//   scalarizes to s_load; emb row address = SGPR base + lane*4, so the VALU
//   only does: weight add, mul, min3, max3, sum, 1x v_perm pack per pair.
//   Raw high-16 key halves are bit-transposed per 32-key chunk (verified XS
//   network); the sortable-key sign transform is applied IN PLANE SPACE
//   (S=sign plane: plane15=~S, plane_b^=S) - 17 VALU/chunk instead of
//   ~128. Bit-serial popc median select templated on nct=ceil(n/32).
// Kernel B: tiny MLP 320->128->64->1 + sigmoid, 4 users/block (unchanged).

#define B_ 4096
#define L_ 200
#define D_ 64

template<int NC>
__device__ __forceinline__ uint32_t select_kth(
    const uint32_t (&PL)[7][16], const uint32_t (&alive0)[7], int k)
{
  uint32_t alive[NC];
  int na = 0;
  #pragma unroll
  for (int c = 0; c < NC; ++c) { alive[c] = alive0[c]; na += __popc(alive[c]); }
  uint32_t prefix = 0;
  #pragma unroll
  for (int bb = 15; bb >= 0; --bb) {
    uint32_t t1[NC]; int cnt1 = 0;
    #pragma unroll
    for (int c = 0; c < NC; ++c) {
      t1[c] = alive[c] & PL[c][15 - bb];
      cnt1 += __popc(t1[c]);
    }
    const int cnt0 = na - cnt1;
    const bool zs = (k < cnt0);
    #pragma unroll
    for (int c = 0; c < NC; ++c) alive[c] = zs ? (alive[c] ^ t1[c]) : t1[c];
    na = zs ? cnt0 : cnt1;
    k  = zs ? k : (k - cnt0);
    prefix = zs ? prefix : (prefix | (1u << bb));
  }
  return prefix;
}

__global__ __launch_bounds__(256) void stats_kernel(
    const int* __restrict__ film_hist,
    const float* __restrict__ ratings,
    const int* __restrict__ lengths,
    const int* __restrict__ film_indices,
    const float* __restrict__ emb,
    float* __restrict__ x)
{
  const int t = threadIdx.x;
  const int wv = t >> 6;
  const int lane = t & 63;
  const int b = blockIdx.x * 4 + wv;
  const int n = lengths[b];                  // wave-uniform (s_load)

  // film embedding (issue early; fully coalesced)
  const int fi = film_indices[b];
  const float fev = emb[(size_t)fi * D_ + lane];

  const int*   hp = film_hist + (size_t)b * L_;
  const float* rp = ratings  + (size_t)b * L_;

  // ---- mean rating: coalesced vector loads + wave reduce (no LDS) ----
  float rsum = 0.f;
  #pragma unroll
  for (int j = 0; j < 4; ++j) {
    const int l = lane + 64*j;
    rsum += (l < n) ? rp[l] : 0.f;
  }
  #pragma unroll
  for (int off = 32; off; off >>= 1) rsum += __shfl_xor(rsum, off);
  const float mr1 = 0.1f - rsum / (float)n;  // uniform, lives in VGPR

  // ---- gather + stats + raw bit-plane build: 7 chunks of 32 rows ----
  float vmin = __builtin_inff(), vmax = -__builtin_inff(), vsum = 0.f;
  uint32_t PL[7][16];

  #pragma unroll
  for (int c = 0; c < 7; ++c) {
    if (n > 32*c) {                          // wave-uniform guard
      const bool full = (32*c + 32 <= n);    // wave-uniform
      uint32_t W[16];
      #pragma unroll
      for (int p = 0; p < 16; ++p) {
        const int i0 = 32*c + 2*p, i1 = i0 + 1;
        const int l0 = (i0 < n) ? i0 : (n-1);          // scalar cselect
        const int l1 = (i1 < n) ? i1 : (n-1);
        const int h0 = hp[l0];                         // uniform -> s_load
        const int h1 = hp[l1];
        const float r0 = rp[l0];                       // uniform -> s_load
        const float r1 = rp[l1];
        const float* e0 = emb + (size_t)h0 * D_;       // SGPR-pair base
        const float* e1 = emb + (size_t)h1 * D_;
        const float w0 = e0[lane] * (r0 + mr1);
        const float w1 = e1[lane] * (r1 + mr1);
        vmin = fminf(fminf(vmin, w0), w1);             // v_min3
        vmax = fmaxf(fmaxf(vmax, w0), w1);             // v_max3
        if (full) vsum += w0 + w1;
        else { vsum += (i0 < n) ? w0 : 0.f; vsum += (i1 < n) ? w1 : 0.f; }
        // pack raw high-16 halves of (w1,w0): one v_perm_b32
        W[p] = __builtin_amdgcn_perm(__float_as_uint(w1), __float_as_uint(w0),
                                     0x07060302u);
      }
      // dual 16x16 bit-matrix transpose (verified network) of RAW halves:
      // W'[j] = plane of raw key-bit (15-j); key i at bit (15-(i>>1))+16*(i&1)
      #define XS(k, jj, m) { uint32_t tt = ((W[k] ^ (W[(k)|(jj)] >> (jj))) & (m)); \
                             W[k] ^= tt; W[(k)|(jj)] ^= (tt << (jj)); }
      XS(0,8,0x00FF00FFu) XS(1,8,0x00FF00FFu) XS(2,8,0x00FF00FFu) XS(3,8,0x00FF00FFu)
      XS(4,8,0x00FF00FFu) XS(5,8,0x00FF00FFu) XS(6,8,0x00FF00FFu) XS(7,8,0x00FF00FFu)
      XS(0,4,0x0F0F0F0Fu) XS(1,4,0x0F0F0F0Fu) XS(2,4,0x0F0F0F0Fu) XS(3,4,0x0F0F0F0Fu)
      XS(8,4,0x0F0F0F0Fu) XS(9,4,0x0F0F0F0Fu) XS(10,4,0x0F0F0F0Fu) XS(11,4,0x0F0F0F0Fu)
      XS(0,2,0x33333333u) XS(1,2,0x33333333u) XS(4,2,0x33333333u) XS(5,2,0x33333333u)
      XS(8,2,0x33333333u) XS(9,2,0x33333333u) XS(12,2,0x33333333u) XS(13,2,0x33333333u)
      XS(0,1,0x55555555u) XS(2,1,0x55555555u) XS(4,1,0x55555555u) XS(6,1,0x55555555u)
      XS(8,1,0x55555555u) XS(10,1,0x55555555u) XS(12,1,0x55555555u) XS(14,1,0x55555555u)
      #undef XS
      // sortable-key transform in plane space: key15 = ~sign; key_b = raw_b ^ sign
      {
        const uint32_t S = W[0];             // raw bit15 (sign) plane
        W[0] = ~S;
        #pragma unroll
        for (int j = 1; j < 16; ++j) W[j] ^= S;
      }
      #pragma unroll
      for (int j = 0; j < 16; ++j) PL[c][j] = W[j];
    } else {
      #pragma unroll
      for (int j = 0; j < 16; ++j) PL[c][j] = 0u;
    }
  }

  // ---- alive masks (verified formula, per chunk) ----
  uint32_t alive[7];
  #pragma unroll
  for (int c = 0; c < 7; ++c) {
    int v = n - 32*c; v = (v < 0) ? 0 : (v > 32 ? 32 : v);
    const int ce = (v + 1) >> 1, cf = v >> 1;
    uint32_t a = ((1u << ce) - 1u) << (16 - ce);
    if (cf) a |= ((1u << cf) - 1u) << (32 - cf);
    alive[c] = a;
  }

  // ---- bit-serial select, templated on active chunk count ----
  const int k = (n - 1) >> 1;
  const int nct = (n + 31) >> 5;             // wave-uniform
  uint32_t prefix;
  switch (nct) {
    case 1: prefix = select_kth<1>(PL, alive, k); break;
    case 2: prefix = select_kth<2>(PL, alive, k); break;
    case 3: prefix = select_kth<3>(PL, alive, k); break;
    case 4: prefix = select_kth<4>(PL, alive, k); break;
    case 5: prefix = select_kth<5>(PL, alive, k); break;
    case 6: prefix = select_kth<6>(PL, alive, k); break;
    default: prefix = select_kth<7>(PL, alive, k); break;
  }

  uint32_t key32 = (prefix << 16) | 0x8000u;           // bucket midpoint
  const float med = (prefix & 0x8000u) ? __uint_as_float(key32 ^ 0x80000000u)
                                       : __uint_as_float(~key32);
  const float mean = vsum / (float)n;

  // ---- L2-normalize (wave reduce of 4-term sumsq) and write x ----
  float ss = vmin*vmin + vmax*vmax + mean*mean + med*med;
  #pragma unroll
  for (int off = 32; off; off >>= 1) ss += __shfl_xor(ss, off);
  const float rn = 1.0f / sqrtf(ss);

  float* xb = x + (size_t)b * 320;
  xb[lane]        = vmin * rn;
  xb[64  + lane]  = vmax * rn;
  xb[128 + lane]  = mean * rn;
  xb[192 + lane]  = med  * rn;
  xb[256 + lane]  = fev;
}

#define U_ 4   // users per MLP block -> 1024 blocks

__global__ __launch_bounds__(256) void mlp_kernel(
    const float* __restrict__ x,
    const float* __restrict__ W1, const float* __restrict__ b1,
    const float* __restrict__ W2, const float* __restrict__ b2,
    const float* __restrict__ W3, const float* __restrict__ b3,
    float* __restrict__ out)
{
  __shared__ float xs[U_*320];
  __shared__ float h1s[U_*128];
  __shared__ float h2s[U_*64];
  const int t = threadIdx.x;
  const int u0 = blockIdx.x * U_;

  for (int i = t; i < U_*80; i += 256)
    ((float4*)xs)[i] = ((const float4*)(x + (size_t)u0*320))[i];
  __syncthreads();

  // h1 = relu(x @ W1 + b1): 4 users x 128 out; thread = (j, 2-user group)
  {
    const int j = t & 127, g = t >> 7;
    const int ub = g*2;
    float acc[2];
    const float bj = b1[j];
    acc[0] = bj; acc[1] = bj;
    for (int i = 0; i < 320; i += 4) {
      float w0 = W1[(i+0)*128 + j];
      float w1 = W1[(i+1)*128 + j];
      float w2 = W1[(i+2)*128 + j];
      float w3 = W1[(i+3)*128 + j];
      #pragma unroll
      for (int q = 0; q < 2; ++q) {
        float4 xv = *(const float4*)&xs[(ub+q)*320 + i];   // LDS broadcast in-wave
        acc[q] += xv.x*w0 + xv.y*w1 + xv.z*w2 + xv.w*w3;
      }
    }
    #pragma unroll
    for (int q = 0; q < 2; ++q) h1s[(ub+q)*128 + j] = fmaxf(acc[q], 0.f);
  }
  __syncthreads();

  // h2 = relu(h1 @ W2 + b2): 4 users x 64 out, 1 user per 64-thread group
  {
    const int j = t & 63, g = t >> 6;
    float acc = b2[j];
    for (int i = 0; i < 128; i += 4) {
      float w0 = W2[(i+0)*64 + j];
      float w1 = W2[(i+1)*64 + j];
      float w2 = W2[(i+2)*64 + j];
      float w3 = W2[(i+3)*64 + j];
      float4 hv = *(const float4*)&h1s[g*128 + i];
      acc += hv.x*w0 + hv.y*w1 + hv.z*w2 + hv.w*w3;
    }
    h2s[g*64 + j] = fmaxf(acc, 0.f);
  }
  __syncthreads();

  // out = sigmoid(h2 @ W3 + b3)
  if (t < U_*4) {
    const int u = t >> 2, sub = t & 3;
    float a = 0.f;
    #pragma unroll
    for (int i = 0; i < 16; ++i) a += h2s[u*64 + sub*16 + i] * W3[sub*16 + i];
    a += __shfl_xor(a, 1);
    a += __shfl_xor(a, 2);
    if (sub == 0) out[u0 + u] = 1.f / (1.f + __expf(-(a + b3[0])));
  }
}

extern "C" void kernel_launch(void* const* d_in, const int* in_sizes, int n_in,
                              void* d_out, int out_size, void* d_ws, size_t ws_size,
                              hipStream_t stream) {
  const int*   film_hist = (const int*)d_in[0];
  const float* ratings   = (const float*)d_in[1];
  const int*   lengths   = (const int*)d_in[2];
  const int*   film_idx  = (const int*)d_in[3];
  const float* emb       = (const float*)d_in[4];
  const float* W1 = (const float*)d_in[5];
  const float* b1 = (const float*)d_in[6];
  const float* W2 = (const float*)d_in[7];
  const float* b2 = (const float*)d_in[8];
  const float* W3 = (const float*)d_in[9];
  const float* b3 = (const float*)d_in[10];

  float* xbuf = (float*)d_ws;                 // B*320 f32 = 5.24 MB
  float* outp = (float*)d_out;

  stats_kernel<<<B_/4, 256, 0, stream>>>(film_hist, ratings, lengths, film_idx, emb, xbuf);
  mlp_kernel<<<B_/U_, 256, 0, stream>>>(xbuf, W1, b1, W2, b2, W3, b3, outp);
}

// Round 13
// 59.937 us; speedup vs baseline: 2.6009x; 2.6009x over previous
//
#include <hip/hip_runtime.h>
#include <hip/hip_bf16.h>
#include <stdint.h>

// Recommender: B=4096 users, L=200 history, D=64 emb, F=100000 films.
// Kernel A (stats): ONE USER PER WAVE, lane = dim; 4 independent waves per
//   256-thread block (1024 blocks), ZERO LDS, zero barriers.
//   Row indices/weights are broadcast from the wave's own registers via
//   v_readlane (compile-time lane index per unrolled chunk) -> row base lives
//   in an SGPR pair, loads use a single shared voffset (lane*4): no per-load
//   address VGPRs, no LDS round-trip, 16 loads batched per half-chunk.
//   Keys: raw high-16 halves packed 2/word with v_perm, per-32-key chunk dual
//   16x16 bit-transpose (verified), sortable-sign fix applied in plane space
//   (S = sign plane: plane15 = ~S, plane_b ^= S). Bit-serial popc median
//   select templated on nct = ceil(n/32) (verified, absmax 0).
// Kernel B: tiny MLP 320->128->64->1 + sigmoid, 4 users/block (unchanged).

#define B_ 4096
#define L_ 200
#define D_ 64

template<int NC>
__device__ __forceinline__ uint32_t select_kth(
    const uint32_t (&PL)[7][16], const uint32_t (&alive0)[7], int k)
{
  uint32_t alive[NC];
  int na = 0;
  #pragma unroll
  for (int c = 0; c < NC; ++c) { alive[c] = alive0[c]; na += __popc(alive[c]); }
  uint32_t prefix = 0;
  #pragma unroll
  for (int bb = 15; bb >= 0; --bb) {
    uint32_t t1[NC]; int cnt1 = 0;
    #pragma unroll
    for (int c = 0; c < NC; ++c) {
      t1[c] = alive[c] & PL[c][15 - bb];
      cnt1 += __popc(t1[c]);
    }
    const int cnt0 = na - cnt1;
    const bool zs = (k < cnt0);
    #pragma unroll
    for (int c = 0; c < NC; ++c) alive[c] = zs ? (alive[c] ^ t1[c]) : t1[c];
    na = zs ? cnt0 : cnt1;
    k  = zs ? k : (k - cnt0);
    prefix = zs ? prefix : (prefix | (1u << bb));
  }
  return prefix;
}

__global__ __launch_bounds__(256) void stats_kernel(
    const int* __restrict__ film_hist,
    const float* __restrict__ ratings,
    const int* __restrict__ lengths,
    const int* __restrict__ film_indices,
    const float* __restrict__ emb,
    float* __restrict__ x)
{
  const int t = threadIdx.x;
  const int wv = t >> 6;
  const int lane = t & 63;
  const int b = blockIdx.x * 4 + wv;
  const int n = lengths[b];                  // wave-uniform

  // film embedding (issue early; fully coalesced)
  const int fi = film_indices[b];
  const float fev = emb[(size_t)fi * D_ + lane];

  const int*   hp = film_hist + (size_t)b * L_;
  const float* rp = ratings  + (size_t)b * L_;

  // ---- coalesced history/ratings load into registers + mean rating ----
  int hv[4]; float rv[4]; float rsum = 0.f;
  #pragma unroll
  for (int j = 0; j < 4; ++j) {
    const int l = lane + 64*j;
    const bool v = l < n;
    hv[j] = v ? hp[l] : 0;
    rv[j] = v ? rp[l] : 0.f;
    rsum += rv[j];
  }
  #pragma unroll
  for (int off = 32; off; off >>= 1) rsum += __shfl_xor(rsum, off);
  const float mr1 = 0.1f - rsum / (float)n;
  float wtv[4];
  #pragma unroll
  for (int j = 0; j < 4; ++j) wtv[j] = rv[j] + mr1;    // per-row weights

  // ---- gather + stats + raw bit-plane build: 7 chunks of 32 rows ----
  float vmin = __builtin_inff(), vmax = -__builtin_inff(), vsum = 0.f;
  uint32_t PL[7][16];

  #pragma unroll
  for (int c = 0; c < 7; ++c) {
    uint32_t* Wc = PL[c];
    if (n > 32*c) {                          // wave-uniform guard
      const bool full = (32*c + 32 <= n);    // wave-uniform
      #pragma unroll
      for (int hh = 0; hh < 2; ++hh) {       // two half-chunks of 16 rows
        float ev[16], wt[16];
        #pragma unroll
        for (int i = 0; i < 16; ++i) {       // SGPR-based loads, batched
          const int li = 32*(c & 1) + 16*hh + i;       // compile-time lane
          const int hrow = __builtin_amdgcn_readlane(hv[c >> 1], li);
          ev[i] = emb[(size_t)(uint32_t)hrow * D_ + lane];
          wt[i] = __uint_as_float(
              __builtin_amdgcn_readlane(__float_as_uint(wtv[c >> 1]), li));
        }
        #pragma unroll
        for (int p = 0; p < 8; ++p) {
          const int i0 = 32*c + 16*hh + 2*p, i1 = i0 + 1;
          const float w0 = ev[2*p]   * wt[2*p];
          const float w1 = ev[2*p+1] * wt[2*p+1];
          if (full) {
            vmin = fminf(fminf(vmin, w0), w1);         // v_min3
            vmax = fmaxf(fmaxf(vmax, w0), w1);         // v_max3
            vsum += w0 + w1;
          } else {
            vmin = fminf(vmin, (i0 < n) ? w0 :  __builtin_inff());
            vmin = fminf(vmin, (i1 < n) ? w1 :  __builtin_inff());
            vmax = fmaxf(vmax, (i0 < n) ? w0 : -__builtin_inff());
            vmax = fmaxf(vmax, (i1 < n) ? w1 : -__builtin_inff());
            vsum += (i0 < n) ? w0 : 0.f;
            vsum += (i1 < n) ? w1 : 0.f;
          }
          // pack raw high-16 halves of (w1,w0): one v_perm_b32
          Wc[8*hh + p] = __builtin_amdgcn_perm(__float_as_uint(w1),
                                               __float_as_uint(w0),
                                               0x07060302u);
        }
      }
      // dual 16x16 bit-matrix transpose (verified network) of RAW halves:
      // Wc[j] = plane of raw key-bit (15-j); key i at bit (15-(i>>1))+16*(i&1)
      #define XS(k, jj, m) { uint32_t tt = ((Wc[k] ^ (Wc[(k)|(jj)] >> (jj))) & (m)); \
                             Wc[k] ^= tt; Wc[(k)|(jj)] ^= (tt << (jj)); }
      XS(0,8,0x00FF00FFu) XS(1,8,0x00FF00FFu) XS(2,8,0x00FF00FFu) XS(3,8,0x00FF00FFu)
      XS(4,8,0x00FF00FFu) XS(5,8,0x00FF00FFu) XS(6,8,0x00FF00FFu) XS(7,8,0x00FF00FFu)
      XS(0,4,0x0F0F0F0Fu) XS(1,4,0x0F0F0F0Fu) XS(2,4,0x0F0F0F0Fu) XS(3,4,0x0F0F0F0Fu)
      XS(8,4,0x0F0F0F0Fu) XS(9,4,0x0F0F0F0Fu) XS(10,4,0x0F0F0F0Fu) XS(11,4,0x0F0F0F0Fu)
      XS(0,2,0x33333333u) XS(1,2,0x33333333u) XS(4,2,0x33333333u) XS(5,2,0x33333333u)
      XS(8,2,0x33333333u) XS(9,2,0x33333333u) XS(12,2,0x33333333u) XS(13,2,0x33333333u)
      XS(0,1,0x55555555u) XS(2,1,0x55555555u) XS(4,1,0x55555555u) XS(6,1,0x55555555u)
      XS(8,1,0x55555555u) XS(10,1,0x55555555u) XS(12,1,0x55555555u) XS(14,1,0x55555555u)
      #undef XS
      // sortable-key transform in plane space: key15 = ~sign; key_b = raw_b ^ sign
      {
        const uint32_t S = Wc[0];            // raw bit15 (sign) plane
        Wc[0] = ~S;
        #pragma unroll
        for (int j = 1; j < 16; ++j) Wc[j] ^= S;
      }
    } else {
      #pragma unroll
      for (int j = 0; j < 16; ++j) Wc[j] = 0u;
    }
  }

  // ---- alive masks (verified formula, per chunk) ----
  uint32_t alive[7];
  #pragma unroll
  for (int c = 0; c < 7; ++c) {
    int v = n - 32*c; v = (v < 0) ? 0 : (v > 32 ? 32 : v);
    const int ce = (v + 1) >> 1, cf = v >> 1;
    uint32_t a = ((1u << ce) - 1u) << (16 - ce);
    if (cf) a |= ((1u << cf) - 1u) << (32 - cf);
    alive[c] = a;
  }

  // ---- bit-serial select, templated on active chunk count ----
  const int k = (n - 1) >> 1;
  const int nct = (n + 31) >> 5;             // wave-uniform
  uint32_t prefix;
  switch (nct) {
    case 1: prefix = select_kth<1>(PL, alive, k); break;
    case 2: prefix = select_kth<2>(PL, alive, k); break;
    case 3: prefix = select_kth<3>(PL, alive, k); break;
    case 4: prefix = select_kth<4>(PL, alive, k); break;
    case 5: prefix = select_kth<5>(PL, alive, k); break;
    case 6: prefix = select_kth<6>(PL, alive, k); break;
    default: prefix = select_kth<7>(PL, alive, k); break;
  }

  uint32_t key32 = (prefix << 16) | 0x8000u;           // bucket midpoint
  const float med = (prefix & 0x8000u) ? __uint_as_float(key32 ^ 0x80000000u)
                                       : __uint_as_float(~key32);
  const float mean = vsum / (float)n;

  // ---- L2-normalize (wave reduce of 4-term sumsq) and write x ----
  float ss = vmin*vmin + vmax*vmax + mean*mean + med*med;
  #pragma unroll
  for (int off = 32; off; off >>= 1) ss += __shfl_xor(ss, off);
  const float rn = 1.0f / sqrtf(ss);

  float* xb = x + (size_t)b * 320;
  xb[lane]        = vmin * rn;
  xb[64  + lane]  = vmax * rn;
  xb[128 + lane]  = mean * rn;
  xb[192 + lane]  = med  * rn;
  xb[256 + lane]  = fev;
}

#define U_ 4   // users per MLP block -> 1024 blocks

__global__ __launch_bounds__(256) void mlp_kernel(
    const float* __restrict__ x,
    const float* __restrict__ W1, const float* __restrict__ b1,
    const float* __restrict__ W2, const float* __restrict__ b2,
    const float* __restrict__ W3, const float* __restrict__ b3,
    float* __restrict__ out)
{
  __shared__ float xs[U_*320];
  __shared__ float h1s[U_*128];
  __shared__ float h2s[U_*64];
  const int t = threadIdx.x;
  const int u0 = blockIdx.x * U_;

  for (int i = t; i < U_*80; i += 256)
    ((float4*)xs)[i] = ((const float4*)(x + (size_t)u0*320))[i];
  __syncthreads();

  // h1 = relu(x @ W1 + b1): 4 users x 128 out; thread = (j, 2-user group)
  {
    const int j = t & 127, g = t >> 7;
    const int ub = g*2;
    float acc[2];
    const float bj = b1[j];
    acc[0] = bj; acc[1] = bj;
    for (int i = 0; i < 320; i += 4) {
      float w0 = W1[(i+0)*128 + j];
      float w1 = W1[(i+1)*128 + j];
      float w2 = W1[(i+2)*128 + j];
      float w3 = W1[(i+3)*128 + j];
      #pragma unroll
      for (int q = 0; q < 2; ++q) {
        float4 xv = *(const float4*)&xs[(ub+q)*320 + i];   // LDS broadcast in-wave
        acc[q] += xv.x*w0 + xv.y*w1 + xv.z*w2 + xv.w*w3;
      }
    }
    #pragma unroll
    for (int q = 0; q < 2; ++q) h1s[(ub+q)*128 + j] = fmaxf(acc[q], 0.f);
  }
  __syncthreads();

  // h2 = relu(h1 @ W2 + b2): 4 users x 64 out, 1 user per 64-thread group
  {
    const int j = t & 63, g = t >> 6;
    float acc = b2[j];
    for (int i = 0; i < 128; i += 4) {
      float w0 = W2[(i+0)*64 + j];
      float w1 = W2[(i+1)*64 + j];
      float w2 = W2[(i+2)*64 + j];
      float w3 = W2[(i+3)*64 + j];
      float4 hv = *(const float4*)&h1s[g*128 + i];
      acc += hv.x*w0 + hv.y*w1 + hv.z*w2 + hv.w*w3;
    }
    h2s[g*64 + j] = fmaxf(acc, 0.f);
  }
  __syncthreads();

  // out = sigmoid(h2 @ W3 + b3)
  if (t < U_*4) {
    const int u = t >> 2, sub = t & 3;
    float a = 0.f;
    #pragma unroll
    for (int i = 0; i < 16; ++i) a += h2s[u*64 + sub*16 + i] * W3[sub*16 + i];
    a += __shfl_xor(a, 1);
    a += __shfl_xor(a, 2);
    if (sub == 0) out[u0 + u] = 1.f / (1.f + __expf(-(a + b3[0])));
  }
}

extern "C" void kernel_launch(void* const* d_in, const int* in_sizes, int n_in,
                              void* d_out, int out_size, void* d_ws, size_t ws_size,
                              hipStream_t stream) {
  const int*   film_hist = (const int*)d_in[0];
  const float* ratings   = (const float*)d_in[1];
  const int*   lengths   = (const int*)d_in[2];
  const int*   film_idx  = (const int*)d_in[3];
  const float* emb       = (const float*)d_in[4];
  const float* W1 = (const float*)d_in[5];
  const float* b1 = (const float*)d_in[6];
  const float* W2 = (const float*)d_in[7];
  const float* b2 = (const float*)d_in[8];
  const float* W3 = (const float*)d_in[9];
  const float* b3 = (const float*)d_in[10];

  float* xbuf = (float*)d_ws;                 // B*320 f32 = 5.24 MB
  float* outp = (float*)d_out;

  stats_kernel<<<B_/4, 256, 0, stream>>>(film_hist, ratings, lengths, film_idx, emb, xbuf);
  mlp_kernel<<<B_/U_, 256, 0, stream>>>(xbuf, W1, b1, W2, b2, W3, b3, outp);
}